// Round 7
// baseline (165.020 us; speedup 1.0000x reference)
//
#include <hip/hip_runtime.h>

// R7: 32-row tiles (R6 geometry) + wide-LDS restructure.
//   s_in[42 x 80]           : input rows gy0-5..gy0+36, cols -5..74 zero-padded (bufA)
//   t1I[37 pairs x 172]     : V-up, ROW-PAIR interleaved: (row 2m+p, col c) at
//                             m*172 + 2c + p. S1 writes b128, S2 reads b128.   (bufB)
//   t3I[37 pairs x 132]     : H-result, same interleave; S2 writes b128,
//                             S4 reads row-pairs as single b64.                (bufA)
// LDS = (4884 + 6364 + 24)*4 ~= 44 KB -> 3 blocks/CU (24 waves).
// Rationale: R5 (-30% VALU)->flat, R6 (-12% LDS)->flat, R3 (+15% ops)->+15%:
// both pipes ~60% busy, poorly overlapped; floor ~ sum of pipe cycles. This
// round cuts LDS cycles ~30% at equal VALU: all LDS ops widened to b64/b128.
#define SIN  80
#define ST1I 172
#define ST3I 132

typedef float v2f __attribute__((ext_vector_type(2)));

static __device__ __forceinline__ v2f fma2(v2f a, v2f b, v2f c) {
    return __builtin_elementwise_fma(a, b, c);
}
static __device__ __forceinline__ v2f bcast2(float s) { v2f r; r.x = s; r.y = s; return r; }
static __device__ __forceinline__ v2f mk2(float a, float b) { v2f r; r.x = a; r.y = b; return r; }

__global__ __launch_bounds__(512, 4)
void synth_fused(const float* __restrict__ x, const float* __restrict__ bias,
                 const float* __restrict__ fu, const float* __restrict__ fd,
                 float* __restrict__ out)
{
    __shared__ __align__(16) float bufA[4884];   // s_in 42x80=3360 | t3I 37x132=4884
    __shared__ __align__(16) float bufB[6364];   // t1I 37x172=6364
    __shared__ float sfilt[24];
    float* const s_in = bufA;
    float* const s_t3 = bufA;
    float* const s_t1 = bufB;

    const int tid  = threadIdx.x;
    const int bx   = blockIdx.x;
    const int tile = bx & 1;
    const int nc   = bx >> 1;
    const int gy0  = tile << 5;

    if (tid < 24) sfilt[tid] = (tid < 12) ? fu[tid] : fd[tid - 12];
    const float bc = bias[nc & 511];
    const float* __restrict__ xc = x + ((size_t)nc << 12);

    // ---- S0: load 42 rows x 64 cols (float4, coalesced) + zero pad cols ----
    #pragma unroll
    for (int it = 0; it < 2; ++it) {
        int idx = tid + (it << 9);
        if (idx < 672) {                         // 42 rows * 16 float4
            int r  = idx >> 4;
            int c4 = (idx & 15) << 2;
            int gy = gy0 - 5 + r;
            float4 v = make_float4(0.f, 0.f, 0.f, 0.f);
            if ((unsigned)gy < 64u)
                v = *reinterpret_cast<const float4*>(xc + (gy << 6) + c4);
            float* dst = s_in + r * SIN + 5 + c4;
            dst[0] = v.x; dst[1] = v.y; dst[2] = v.z; dst[3] = v.w;
        }
    }
    #pragma unroll
    for (int it = 0; it < 2; ++it) {                 // 42*16 pad slots (cols 0..4, 69..79)
        int idx = tid + (it << 9);
        if (idx < 672) {
            int r  = idx >> 4;
            int pc = idx & 15;
            int c  = (pc < 5) ? pc : (64 + pc);
            s_in[r * SIN + c] = 0.0f;
        }
    }
    __syncthreads();

    float u0[12], gs[12];
    #pragma unroll
    for (int k = 0; k < 12; ++k) { u0[k] = sfilt[k]; gs[k] = sfilt[23 - k]; }
    v2f gpk[6];
    #pragma unroll
    for (int j = 0; j < 6; ++j) gpk[j] = mk2(gs[2*j], gs[2*j + 1]);

    // ---- S1: vertical x2 up, 2 cols/thread. 444 thr = 12 m-groups x 37 col-pairs ----
    // group g owns pairs m0..m0+cnt-1, m0 = 3g+(g>0), cnt = 3+(g==0)  (total 37).
    // t1[2m+p][c] = sum_j u0[10+p-2j]*s_in[m+j][c]; write b128 {E(c),O(c),E(c+1),O(c+1)}
    if (tid < 444) {
        const int g  = tid / 37;
        const int c2 = tid - 37 * g;
        const int m0 = 3 * g + (g > 0);
        const float* ip = s_in + m0 * SIN + 2 * c2;
        v2f rv[9];
        #pragma unroll
        for (int j = 0; j < 8; ++j) rv[j] = *reinterpret_cast<const v2f*>(ip + j * SIN);
        rv[8] = (g == 0) ? *reinterpret_cast<const v2f*>(ip + 8 * SIN) : bcast2(0.f);
        float* op = s_t1 + m0 * ST1I + 4 * c2;
        #pragma unroll
        for (int mm = 0; mm < 3; ++mm) {
            v2f aE = rv[mm] * u0[10];
            v2f aO = rv[mm] * u0[11];
            #pragma unroll
            for (int j = 1; j < 6; ++j) {
                aE = fma2(rv[mm + j], bcast2(u0[10 - 2*j]), aE);
                aO = fma2(rv[mm + j], bcast2(u0[11 - 2*j]), aO);
            }
            float4 o4; o4.x = aE.x; o4.y = aO.x; o4.z = aE.y; o4.w = aO.y;
            *reinterpret_cast<float4*>(op + mm * ST1I) = o4;
        }
        if (g == 0) {
            v2f aE = rv[3] * u0[10];
            v2f aO = rv[3] * u0[11];
            #pragma unroll
            for (int j = 1; j < 6; ++j) {
                aE = fma2(rv[3 + j], bcast2(u0[10 - 2*j]), aE);
                aO = fma2(rv[3 + j], bcast2(u0[11 - 2*j]), aO);
            }
            float4 o4; o4.x = aE.x; o4.y = aO.x; o4.z = aE.y; o4.w = aO.y;
            *reinterpret_cast<float4*>(op + 3 * ST1I) = o4;
        }
    }
    __syncthreads();

    // ---- S2: fused H-up + lrelu/clamp + H-down, 2 rows/thread (row-packed v2f) ----
    // 296 thr = 37 row-pairs x 8 col-chunks; chunk q owns out cols 8q..8q+7.
    // Reads 9 b128 (cols 8q..8q+17, all valid); t2 pairs m 0..25; writes 4 b128.
    {
        const float S42 = 4.0f * 1.41421356237309515f;   // up-gain 4 * lrelu sqrt2
        float us2[12];
        #pragma unroll
        for (int k = 0; k < 12; ++k) us2[k] = u0[k] * S42;
        const float bcs = bc * 1.41421356237309515f;

        if (tid < 296) {
            const int rp = tid >> 3;
            const int q  = tid & 7;
            const float* t1r = s_t1 + rp * ST1I + 16 * q;
            v2f wp[18];
            #pragma unroll
            for (int k = 0; k < 9; ++k) {
                float4 f4 = *reinterpret_cast<const float4*>(t1r + 4 * k);
                wp[2*k]   = mk2(f4.x, f4.y);
                wp[2*k+1] = mk2(f4.z, f4.w);
            }
            auto T2 = [&](int m) -> v2f {
                v2f acc = bcast2(bcs);
                #pragma unroll
                for (int j = 0; j < 6; ++j)
                    acc = fma2(wp[(m >> 1) + j], bcast2(us2[10 + (m & 1) - 2*j]), acc);
                v2f s2 = acc * 0.2f;
                return mk2(__builtin_amdgcn_fmed3f(fmaxf(acc.x, s2.x), -256.f, 256.f),
                           __builtin_amdgcn_fmed3f(fmaxf(acc.y, s2.y), -256.f, 256.f));
            };
            v2f t2p[26];
            #pragma unroll
            for (int m = 0; m < 10; ++m) t2p[m] = T2(m);
            float* t3r = s_t3 + rp * ST3I + 16 * q;
            v2f aPrev;
            #pragma unroll
            for (int i = 0; i < 8; ++i) {
                t2p[2*i + 10] = T2(2*i + 10);
                t2p[2*i + 11] = T2(2*i + 11);
                v2f a = t2p[2*i] * gs[0];
                #pragma unroll
                for (int k = 1; k < 12; ++k)
                    a = fma2(t2p[2*i + k], bcast2(gs[k]), a);
                if (i & 1) {
                    float4 o4; o4.x = aPrev.x; o4.y = aPrev.y; o4.z = a.x; o4.w = a.y;
                    *reinterpret_cast<float4*>(t3r + 2 * (i - 1)) = o4;
                } else {
                    aPrev = a;
                }
            }
        }
    }
    __syncthreads();

    // ---- S4: vertical /2 down, 1 col/thread, 512 thr (rc 0..7, c 0..63) ----
    // out rows gy0+4rc..+3; vp[j] = b64 {t3[2(4rc+j)][c], t3[2(4rc+j)+1][c]}
    {
        const int c  = tid & 63;
        const int rc = tid >> 6;
        const float* t3c = s_t3 + (rc << 2) * ST3I + 2 * c;
        v2f vp[9];
        #pragma unroll
        for (int j = 0; j < 9; ++j) vp[j] = *reinterpret_cast<const v2f*>(t3c + j * ST3I);
        float* op = out + ((size_t)nc << 12) + ((size_t)(gy0 + (rc << 2)) << 6) + c;
        #pragma unroll
        for (int s = 0; s < 4; ++s) {
            v2f acc = vp[s] * gpk[0];
            #pragma unroll
            for (int j = 1; j < 6; ++j) acc = fma2(vp[s + j], gpk[j], acc);
            op[(size_t)(s << 6)] = acc.x + acc.y;
        }
    }
}

extern "C" void kernel_launch(void* const* d_in, const int* in_sizes, int n_in,
                              void* d_out, int out_size, void* d_ws, size_t ws_size,
                              hipStream_t stream) {
    const float* x    = (const float*)d_in[0];
    const float* bias = (const float*)d_in[1];
    const float* fu   = (const float*)d_in[2];
    const float* fd   = (const float*)d_in[3];
    float* out        = (float*)d_out;

    dim3 grid(8 * 512 * 2);   // (n*c) x 2 row-tiles of 32x64
    dim3 block(512);
    hipLaunchKernelGGL(synth_fused, grid, block, 0, stream, x, bias, fu, fd, out);
}

// Round 9
// 154.161 us; speedup vs baseline: 1.0704x; 1.0704x over previous
//
#include <hip/hip_runtime.h>

// Tile: 16 output rows x 64 output cols; 4 tiles per (n,c); grid 16384.
// R8: R5 skeleton (75.4us) + LDS-instruction compression, nothing else.
// R9: identical resubmit (R8 bench died on container infra, no data).
//   S0 load -> S1 V-up(x2) -> S2 [H-up + act + H-down] fused -> S4 V-down + store.
//   s_in[26 x 80] : input rows gy0-5..gy0+20, cols -5..74 zero-padded   (bufA)
//   t1  [42 x 84] : vertical x2 up, cols 0..73 valid. ST1=84 (not 80):  (bufB)
//                   at 80, S2's b128 reads collide at dr=2 (160%32==0);
//                   at 84, collision moves to dr=8 -> near-uniform banks.
//   t3  [42 x 72] : H-up+act+H-down result, cols 0..63 valid            (bufA)
// LDS = (3024 + 3536 + 24)*4 = 25.7 KB -> 6 blocks/CU (24 waves).
// LDS wave-instr/block ~240 -> ~150:
//   S1: b64 x(12r+14w) at 111 thr (was b32 x26 at 222 thr) - uniform banks
//   S2: w[22] as 5xb128+1xb64 (was 11 b64)
//   S4: 2 cols/thr b64 x18r at 128 thr (was b32 x18 at 256 thr); rc-stride
//       576%32==0 but uniform 4 words/bank = minimum cycles (free);
//       col-packed math: 12 fma2/out-row, no hadd.
#define SIN 80
#define ST1 84
#define ST3 72

typedef float v2f __attribute__((ext_vector_type(2)));

static __device__ __forceinline__ v2f fma2(v2f a, v2f b, v2f c) {
    return __builtin_elementwise_fma(a, b, c);
}
static __device__ __forceinline__ v2f bcast2(float s) { v2f r; r.x = s; r.y = s; return r; }
static __device__ __forceinline__ v2f mk2(float a, float b) { v2f r; r.x = a; r.y = b; return r; }

__global__ __launch_bounds__(256, 4)
void synth_fused(const float* __restrict__ x, const float* __restrict__ bias,
                 const float* __restrict__ fu, const float* __restrict__ fd,
                 float* __restrict__ out)
{
    __shared__ __align__(16) float bufA[3024];   // s_in 26x80=2080 | t3 42x72=3024
    __shared__ __align__(16) float bufB[3536];   // t1 42x84=3528 + slack (q=5 reads to 3525)
    __shared__ float sfilt[24];
    float* const s_in = bufA;
    float* const s_t3 = bufA;
    float* const s_t1 = bufB;

    const int tid  = threadIdx.x;
    const int bx   = blockIdx.x;
    const int tile = bx & 3;
    const int nc   = bx >> 2;
    const int gy0  = tile << 4;

    if (tid < 24) sfilt[tid] = (tid < 12) ? fu[tid] : fd[tid - 12];
    const float bc = bias[nc & 511];
    const float* __restrict__ xc = x + ((size_t)nc << 12);

    // ---- S0: load 26 rows x 64 cols (float4 global, coalesced) + zero pad ----
    #pragma unroll
    for (int it = 0; it < 2; ++it) {
        int idx = tid + it * 256;
        if (idx < 416) {                         // 26 rows * 16 float4
            int r  = idx >> 4;
            int c4 = (idx & 15) << 2;
            int gy = gy0 - 5 + r;
            float4 v = make_float4(0.f, 0.f, 0.f, 0.f);
            if ((unsigned)gy < 64u)
                v = *reinterpret_cast<const float4*>(xc + (gy << 6) + c4);
            float* dst = s_in + r * SIN + 5 + c4;
            dst[0] = v.x; dst[1] = v.y; dst[2] = v.z; dst[3] = v.w;
        }
    }
    #pragma unroll
    for (int it = 0; it < 2; ++it) {                 // 26*16 pad slots (cols 0..4, 69..79)
        int idx = tid + it * 256;
        if (idx < 416) {
            int r  = idx >> 4;
            int pc = idx & 15;
            int c  = (pc < 5) ? pc : (64 + pc);
            s_in[r * SIN + c] = 0.0f;
        }
    }
    __syncthreads();

    // filter registers
    float u0[12], gs[12];
    #pragma unroll
    for (int k = 0; k < 12; ++k) { u0[k] = sfilt[k]; gs[k] = sfilt[23 - k]; }   // gs[k]=fd[11-k]
    v2f gpk[6];
    #pragma unroll
    for (int j = 0; j < 6; ++j) gpk[j] = mk2(gs[2*j], gs[2*j + 1]);

    // ---- S1: vertical x2 up, 2 cols/thread b64. 111 thr (g3 0..2, c2 0..36) ----
    // {t1[2m][2c2..+1], t1[2m+1][...]} = sum_j u0[10/11-2j] * s_in[7g3+m+j][2c2..+1]
    if (tid < 111) {
        const int g3 = tid / 37;
        const int c2 = tid - 37 * g3;
        const float* ip = s_in + (7 * g3) * SIN + 2 * c2;
        v2f rv[12];
        #pragma unroll
        for (int j = 0; j < 12; ++j) rv[j] = *reinterpret_cast<const v2f*>(ip + j * SIN);
        float* op = s_t1 + (14 * g3) * ST1 + 2 * c2;
        #pragma unroll
        for (int m = 0; m < 7; ++m) {
            v2f aE = rv[m] * u0[10];
            v2f aO = rv[m] * u0[11];
            #pragma unroll
            for (int j = 1; j < 6; ++j) {
                aE = fma2(rv[m + j], bcast2(u0[10 - 2*j]), aE);
                aO = fma2(rv[m + j], bcast2(u0[11 - 2*j]), aO);
            }
            *reinterpret_cast<v2f*>(op + (2*m) * ST1)     = aE;
            *reinterpret_cast<v2f*>(op + (2*m + 1) * ST1) = aO;
        }
    }
    __syncthreads();

    // fold x4 up-gain AND sqrt2 act-gain into H-up taps; sqrt2 into bias
    const float S42 = 4.0f * 1.41421356237309515f;
    v2f upk2[6];
    #pragma unroll
    for (int j = 0; j < 6; ++j) upk2[j] = mk2(u0[10 - 2*j] * S42, u0[11 - 2*j] * S42);
    const float bcs = bc * 1.41421356237309515f;

    // ---- S2: fused H-up + lrelu/clamp + H-down. 252 thr (r 0..41, q 0..5) ----
    // t2p[i] = act( sum_j upk2[j]*{w[i+j]}bcast + {bcs,bcs} ),  i 0..16
    //   act(z) = med3(max(z, 0.2z), -256, 256)   [sqrt2 already in taps/bias]
    // t3[r][12q+oi] = hadd( sum_j gpk[j]*t2p[oi+j] ),  oi 0..11
    // q=5: t1 cols >=74 garbage -> feeds only t3 cols >=64 (pad, never read).
    if (tid < 252) {
        const int r = tid / 6;
        const int q = tid - 6 * r;
        const float* t1r = s_t1 + r * ST1 + 12 * q;
        float w[22];
        #pragma unroll
        for (int j = 0; j < 5; ++j) {                  // 5 x b128 (16B-aligned: 84r+12q ≡ 0 mod 4)
            float4 v4 = *reinterpret_cast<const float4*>(t1r + 4 * j);
            w[4*j] = v4.x; w[4*j+1] = v4.y; w[4*j+2] = v4.z; w[4*j+3] = v4.w;
        }
        { v2f v2 = *reinterpret_cast<const v2f*>(t1r + 20); w[20] = v2.x; w[21] = v2.y; }
        const v2f bc2 = bcast2(bcs);
        v2f t2p[17];
        #pragma unroll
        for (int i = 0; i < 17; ++i) {
            v2f acc = bc2;
            #pragma unroll
            for (int j = 0; j < 6; ++j)
                acc = fma2(upk2[j], bcast2(w[i + j]), acc);
            v2f mx = __builtin_elementwise_max(acc, acc * 0.2f);
            t2p[i] = mk2(__builtin_amdgcn_fmed3f(mx.x, -256.0f, 256.0f),
                         __builtin_amdgcn_fmed3f(mx.y, -256.0f, 256.0f));
        }
        float* t3r = s_t3 + r * ST3 + 12 * q;
        #pragma unroll
        for (int i = 0; i < 3; ++i) {
            float4 o4;
            float* op = &o4.x;
            #pragma unroll
            for (int s = 0; s < 4; ++s) {
                const int oi = 4 * i + s;
                v2f acc = gpk[0] * t2p[oi];
                #pragma unroll
                for (int j = 1; j < 6; ++j) acc = fma2(gpk[j], t2p[oi + j], acc);
                op[s] = acc.x + acc.y;
            }
            *reinterpret_cast<float4*>(t3r + 4 * i) = o4;
        }
    }
    __syncthreads();

    // ---- S4: vertical /2 down, 2 cols/thread b64. 128 thr (rc 0..3, c2 0..31) ----
    // out rows gy0+4rc..+3 at cols 2c2,2c2+1; reads t3 rows 8rc..8rc+17 as b64.
    // Col-packed: acc2 over the 2 cols, 12 scalar-bcast taps, no hadd.
    if (tid < 128) {
        const int c2 = tid & 31;
        const int rc = tid >> 5;
        const float* t3c = s_t3 + (rc << 3) * ST3 + 2 * c2;
        v2f wv[18];
        #pragma unroll
        for (int j = 0; j < 18; ++j) wv[j] = *reinterpret_cast<const v2f*>(t3c + j * ST3);
        float* op = out + ((size_t)nc << 12) + ((size_t)(gy0 + (rc << 2)) << 6) + 2 * c2;
        #pragma unroll
        for (int i = 0; i < 4; ++i) {
            v2f acc = wv[2*i] * gs[0];
            #pragma unroll
            for (int k = 1; k < 12; ++k)
                acc = fma2(wv[2*i + k], bcast2(gs[k]), acc);
            *reinterpret_cast<v2f*>(op + (size_t)(i << 6)) = acc;
        }
    }
}

extern "C" void kernel_launch(void* const* d_in, const int* in_sizes, int n_in,
                              void* d_out, int out_size, void* d_ws, size_t ws_size,
                              hipStream_t stream) {
    const float* x    = (const float*)d_in[0];
    const float* bias = (const float*)d_in[1];
    const float* fu   = (const float*)d_in[2];
    const float* fd   = (const float*)d_in[3];
    float* out        = (float*)d_out;

    dim3 grid(8 * 512 * 4);   // (n*c) x 4 row-tiles of 16x64
    dim3 block(256);
    hipLaunchKernelGGL(synth_fused, grid, block, 0, stream, x, bias, fu, fd, out);
}